// Round 12
// baseline (288.527 us; speedup 1.0000x reference)
//
#include <hip/hip_runtime.h>

#define NN 50000
#define NE 1500000
#define DD 128
#define NRANGE ((NN + 255) / 256)      // 196 dst-ranges of 256 nodes
#define NBUCK (3 * NRANGE)             // 588 (rel, range) buckets
#define BINB 512                       // binning blocks (2 per CU)
#define CHUNK ((NE + BINB - 1) / BINB) // 2930 edges per binning block
#define NH2 (NBUCK * BINB)             // 301056 hist2 entries
#define GCONV ((NN * DD / 4 + 255) / 256)  // 6250 to_bf16 blocks
#define GGEMM ((NN + 63) / 64)         // 782 mm blocks
#define GGATH ((NN + 7) / 8)           // 6250 gather blocks

typedef __attribute__((ext_vector_type(8))) short short8;
typedef __attribute__((ext_vector_type(4))) float f32x4;

__device__ __forceinline__ ushort f2b(float x) {
    uint u = __float_as_uint(x);
    u += 0x7FFFu + ((u >> 16) & 1u);
    return (ushort)(u >> 16);
}
__device__ __forceinline__ float b2f(ushort b) {
    return __uint_as_float(((uint)b) << 16);
}

// ---------------- scan helpers ----------------
__global__ __launch_bounds__(256) void scan_block(
    const int* __restrict__ cnt, int* __restrict__ ptr, int* __restrict__ part, int n)
{
    __shared__ int s[256];
    int i = blockIdx.x * 256 + threadIdx.x;
    int v = (i < n) ? cnt[i] : 0;
    s[threadIdx.x] = v;
    __syncthreads();
    #pragma unroll
    for (int off = 1; off < 256; off <<= 1) {
        int t = (threadIdx.x >= off) ? s[threadIdx.x - off] : 0;
        __syncthreads();
        s[threadIdx.x] += t;
        __syncthreads();
    }
    if (i < n) ptr[i] = s[threadIdx.x] - v;
    if (threadIdx.x == 255) part[blockIdx.x] = s[255];
}

__global__ void scan_partials(int* __restrict__ part, int nb)
{
    int lane = threadIdx.x;
    int run = 0;
    for (int base = 0; base < nb; base += 64) {
        int i = base + lane;
        int v = (i < nb) ? part[i] : 0;
        int x = v;
        #pragma unroll
        for (int off = 1; off < 64; off <<= 1) {
            int t = __shfl_up(x, off);
            if (lane >= off) x += t;
        }
        if (i < nb) part[i] = run + x - v;
        run += __shfl(x, 63);
    }
}

__global__ __launch_bounds__(256) void scan_add(
    int* __restrict__ ptr, const int* __restrict__ part, int n)
{
    int i = blockIdx.x * 256 + threadIdx.x;
    if (i >= n) return;
    ptr[i] += part[blockIdx.x];
}

// ---------------- fused prologue: histB | to_bf16 | prep_w ----------------
__global__ __launch_bounds__(256) void prep_all(
    const int* __restrict__ dst, const int* __restrict__ attr, int* __restrict__ hist2,
    const float* __restrict__ x, ushort* __restrict__ xb,
    const float* __restrict__ Ws_s, const float* __restrict__ Ws_k, ushort* __restrict__ wt)
{
    __shared__ int lh[NBUCK];
    int b = blockIdx.x, tid = threadIdx.x;
    if (b < BINB) {
        for (int i = tid; i < NBUCK; i += 256) lh[i] = 0;
        __syncthreads();
        int lo = b * CHUNK, hi = lo + CHUNK; if (hi > NE) hi = NE;
        for (int e = lo + tid; e < hi; e += 256)
            atomicAdd(&lh[attr[e] * NRANGE + (dst[e] >> 8)], 1);
        __syncthreads();
        for (int i = tid; i < NBUCK; i += 256) hist2[i * BINB + b] = lh[i];
    } else if (b < BINB + GCONV) {
        int i = (b - BINB) * 256 + tid;
        if (i < NN * DD / 4) {
            float4 v = ((const float4*)x)[i];
            ushort4 o;
            o.x = f2b(v.x); o.y = f2b(v.y); o.z = f2b(v.z); o.w = f2b(v.w);
            ((ushort4*)xb)[i] = o;
        }
    } else {
        int i = (b - BINB - GCONV) * 256 + tid;
        if (i < 9 * 4096) {
            int m = i >> 12;
            int f = (i & 4095) * 4;
            int k = f >> 7, n = f & 127;
            const int tk[6] = {0, 3, 4, 6, 7, 8};
            const float* W = (m < 3) ? (Ws_s + (size_t)m * 16384)
                                     : (Ws_k + (size_t)tk[m - 3] * 16384);
            float4 v = *(const float4*)(W + (size_t)k * DD + n);
            ushort* o = wt + (size_t)m * 16384 + k;
            o[(size_t)(n + 0) * DD] = f2b(v.x);
            o[(size_t)(n + 1) * DD] = f2b(v.y);
            o[(size_t)(n + 2) * DD] = f2b(v.z);
            o[(size_t)(n + 3) * DD] = f2b(v.w);
        }
    }
}

// ---------------- contention-free binning ----------------
__global__ __launch_bounds__(256) void binB(
    const int* __restrict__ src, const int* __restrict__ dst, const int* __restrict__ attr,
    const int* __restrict__ off2, uint* __restrict__ binned)
{
    __shared__ int lc[NBUCK];
    int tid = threadIdx.x, blk = blockIdx.x;
    for (int i = tid; i < NBUCK; i += 256) lc[i] = off2[i * BINB + blk];
    __syncthreads();
    int lo = blk * CHUNK, hi = lo + CHUNK; if (hi > NE) hi = NE;
    for (int e = lo + tid; e < hi; e += 256) {
        int d = dst[e];
        int b = attr[e] * NRANGE + (d >> 8);
        int pos = atomicAdd(&lc[b], 1);
        binned[pos] = (uint)src[e] | ((uint)(d & 255) << 16);   // src < 2^16
    }
}

// per-bucket: derive per-node CSR ptr (LDS hist+scan) and place edges into ssrc
__global__ __launch_bounds__(256) void bucket_finalize(
    const uint* __restrict__ binned, const int* __restrict__ off2,
    int* __restrict__ ptr, int* __restrict__ ssrc)
{
    __shared__ int lh[256];
    __shared__ int sc[256];
    __shared__ int cur[256];
    int b = blockIdx.x, tid = threadIdx.x;
    int rel = b / NRANGE, r0 = (b % NRANGE) << 8;
    int nloc = NN - r0; if (nloc > 256) nloc = 256;
    int lo = off2[b * BINB];
    int hi = (b + 1 < NBUCK) ? off2[(b + 1) * BINB] : NE;
    lh[tid] = 0;
    __syncthreads();
    for (int e = lo + tid; e < hi; e += 256)
        atomicAdd(&lh[(binned[e] >> 16) & 255], 1);
    __syncthreads();
    int v = lh[tid];
    sc[tid] = v;
    __syncthreads();
    #pragma unroll
    for (int off = 1; off < 256; off <<= 1) {
        int t = (tid >= off) ? sc[tid - off] : 0;
        __syncthreads();
        sc[tid] += t;
        __syncthreads();
    }
    int excl = lo + sc[tid] - v;
    if (tid < nloc) ptr[rel * NN + r0 + tid] = excl;
    cur[tid] = excl;
    if (b == NBUCK - 1 && tid == 0) ptr[3 * NN] = NE;
    __syncthreads();
    for (int e = lo + tid; e < hi; e += 256) {
        uint p = binned[e];
        int pos = atomicAdd(&cur[(p >> 16) & 255], 1);
        ssrc[pos] = (int)(p & 0xFFFFu);
    }
}

// ---------------- gather body: 2 nodes per wave, uint2 per lane -------------
__device__ __forceinline__ void gather_body(
    const ushort* __restrict__ h, int rel, ushort* __restrict__ agg,
    const int* __restrict__ ptr, const int* __restrict__ ssrc, int blk, int tid)
{
    int half = (tid >> 5) & 1;
    int sub  = tid & 31;
    int n = blk * 8 + ((tid >> 6) << 1) + half;
    if (n >= NN) return;
    const int* p = ptr + rel * NN + n;
    int s0 = p[0], s1 = p[1];          // broadcast within half-wave
    float A0 = 0.f, A1 = 0.f, A2 = 0.f, A3 = 0.f;
    int e = s0;
    for (; e + 8 <= s1; e += 8) {
        int idx[8];
        #pragma unroll
        for (int j = 0; j < 8; ++j) idx[j] = ssrc[e + j];
        uint2 v[8];
        #pragma unroll
        for (int j = 0; j < 8; ++j)
            v[j] = ((const uint2*)(h + (size_t)idx[j] * DD))[sub];
        #pragma unroll
        for (int j = 0; j < 8; ++j) {
            A0 += b2f((ushort)(v[j].x & 0xFFFFu)); A1 += b2f((ushort)(v[j].x >> 16));
            A2 += b2f((ushort)(v[j].y & 0xFFFFu)); A3 += b2f((ushort)(v[j].y >> 16));
        }
    }
    if (e + 4 <= s1) {
        int i0 = ssrc[e], i1 = ssrc[e + 1], i2 = ssrc[e + 2], i3 = ssrc[e + 3];
        uint2 v0 = ((const uint2*)(h + (size_t)i0 * DD))[sub];
        uint2 v1 = ((const uint2*)(h + (size_t)i1 * DD))[sub];
        uint2 v2 = ((const uint2*)(h + (size_t)i2 * DD))[sub];
        uint2 v3 = ((const uint2*)(h + (size_t)i3 * DD))[sub];
        A0 += b2f((ushort)(v0.x & 0xFFFFu)); A1 += b2f((ushort)(v0.x >> 16));
        A2 += b2f((ushort)(v0.y & 0xFFFFu)); A3 += b2f((ushort)(v0.y >> 16));
        A0 += b2f((ushort)(v1.x & 0xFFFFu)); A1 += b2f((ushort)(v1.x >> 16));
        A2 += b2f((ushort)(v1.y & 0xFFFFu)); A3 += b2f((ushort)(v1.y >> 16));
        A0 += b2f((ushort)(v2.x & 0xFFFFu)); A1 += b2f((ushort)(v2.x >> 16));
        A2 += b2f((ushort)(v2.y & 0xFFFFu)); A3 += b2f((ushort)(v2.y >> 16));
        A0 += b2f((ushort)(v3.x & 0xFFFFu)); A1 += b2f((ushort)(v3.x >> 16));
        A2 += b2f((ushort)(v3.y & 0xFFFFu)); A3 += b2f((ushort)(v3.y >> 16));
        e += 4;
    }
    for (; e < s1; ++e) {
        int s = ssrc[e];
        uint2 v = ((const uint2*)(h + (size_t)s * DD))[sub];
        A0 += b2f((ushort)(v.x & 0xFFFFu)); A1 += b2f((ushort)(v.x >> 16));
        A2 += b2f((ushort)(v.y & 0xFFFFu)); A3 += b2f((ushort)(v.y >> 16));
    }
    uint2 o;
    o.x = (uint)f2b(A0) | ((uint)f2b(A1) << 16);
    o.y = (uint)f2b(A2) | ((uint)f2b(A3) << 16);
    ((uint2*)(agg + (size_t)n * DD))[sub] = o;
}

// ---------------- standalone gather (rel0 of each layer) ----------------
__global__ __launch_bounds__(256) void gather_one(
    const ushort* __restrict__ h, int rel,
    const int* __restrict__ ptr, const int* __restrict__ ssrc,
    ushort* __restrict__ agg)
{
    gather_body(h, rel, agg, ptr, ssrc, blockIdx.x, threadIdx.x);
}

// ---------------- fused layer: mm (+ residual) || independent gathers --------
// OUTMODE 0: write bf16 xbnew only. OUTMODE 1: write f32 xnewf only (final).
template<int NSRC, int OUTMODE, int NG>
__global__ __launch_bounds__(256) void mm_gather(
    const ushort* __restrict__ s0, const ushort* __restrict__ s1,
    const ushort* __restrict__ s2, const ushort* __restrict__ s3,
    const ushort* __restrict__ w0, const ushort* __restrict__ w1,
    const ushort* __restrict__ w2, const ushort* __restrict__ w3,
    const float* __restrict__ b0, const float* __restrict__ b1,
    const float* __restrict__ b2, const float* __restrict__ b3,
    const ushort* __restrict__ xoldb, float* __restrict__ xnewf, ushort* __restrict__ xbnew,
    const ushort* __restrict__ g0tab, int g0rel, ushort* __restrict__ g0out,
    const ushort* __restrict__ g1tab, int g1rel, ushort* __restrict__ g1out,
    const int* __restrict__ ptr, const int* __restrict__ ssrc)
{
    __shared__ ushort Atile[64 * 128];   // XOR-swizzled (mm blocks only)
    const int tid = threadIdx.x;

    if (NG > 0 && blockIdx.x >= GGEMM) {
        int g = blockIdx.x - GGEMM;
        int which = (NG > 1) ? (g / GGATH) : 0;
        gather_body(which ? g1tab : g0tab, which ? g1rel : g0rel,
                    which ? g1out : g0out, ptr, ssrc, g % GGATH, tid);
        return;
    }

    const int wave = tid >> 6, lane = tid & 63;
    const int row0 = blockIdx.x * 64;

    const ushort* srcs[4] = { s0, s1, s2, s3 };
    const ushort* wts[4]  = { w0, w1, w2, w3 };
    const float*  bss[4]  = { b0, b1, b2, b3 };

    float facc[4][2][4];
    #pragma unroll
    for (int rt = 0; rt < 4; ++rt)
        #pragma unroll
        for (int ct = 0; ct < 2; ++ct)
            #pragma unroll
            for (int q = 0; q < 4; ++q) facc[rt][ct][q] = 0.f;

    #pragma unroll
    for (int sidx = 0; sidx < NSRC; ++sidx) {
        const ushort* S = srcs[sidx];
        const ushort* W = wts[sidx];

        __syncthreads();
        for (int i = tid; i < 1024; i += 256) {
            int r = i >> 4, c = i & 15;
            int gr = row0 + r;
            uint4 v = make_uint4(0, 0, 0, 0);
            if (gr < NN) v = ((const uint4*)(S + (size_t)gr * DD))[c];
            int byte = ((r << 8) + (c << 4)) ^ ((r & 7) << 4);
            *((uint4*)((char*)Atile + byte)) = v;
        }
        short8 bfr[2][4];
        #pragma unroll
        for (int ct = 0; ct < 2; ++ct)
            #pragma unroll
            for (int ks = 0; ks < 4; ++ks) {
                int col = (wave << 5) + (ct << 4) + (lane & 15);
                int kb  = (ks << 5) + ((lane >> 4) << 3);
                bfr[ct][ks] = *(const short8*)(W + (size_t)col * DD + kb);
            }
        __syncthreads();

        f32x4 c[4][2];
        #pragma unroll
        for (int rt = 0; rt < 4; ++rt)
            #pragma unroll
            for (int ct = 0; ct < 2; ++ct) c[rt][ct] = (f32x4)(0.f);

        #pragma unroll
        for (int rt = 0; rt < 4; ++rt) {
            int row = (rt << 4) + (lane & 15);
            #pragma unroll
            for (int ks = 0; ks < 4; ++ks) {
                int byte = ((row << 8) + (ks << 6) + ((lane >> 4) << 4)) ^ ((row & 7) << 4);
                short8 a = *((const short8*)((const char*)Atile + byte));
                c[rt][0] = __builtin_amdgcn_mfma_f32_16x16x32_bf16(a, bfr[0][ks], c[rt][0], 0, 0, 0);
                c[rt][1] = __builtin_amdgcn_mfma_f32_16x16x32_bf16(a, bfr[1][ks], c[rt][1], 0, 0, 0);
            }
        }

        const float* B = bss[sidx];
        #pragma unroll
        for (int ct = 0; ct < 2; ++ct) {
            float bb = B[(wave << 5) + (ct << 4) + (lane & 15)];
            #pragma unroll
            for (int rt = 0; rt < 4; ++rt)
                #pragma unroll
                for (int q = 0; q < 4; ++q) {
                    float v = c[rt][ct][q] + bb;
                    facc[rt][ct][q] += v > 0.f ? v : 0.f;
                }
        }
    }

    #pragma unroll
    for (int rt = 0; rt < 4; ++rt)
        #pragma unroll
        for (int q = 0; q < 4; ++q) {
            int row = row0 + (rt << 4) + ((lane >> 4) << 2) + q;
            if (row >= NN) continue;
            #pragma unroll
            for (int ct = 0; ct < 2; ++ct) {
                int col = (wave << 5) + (ct << 4) + (lane & 15);
                size_t off = (size_t)row * DD + col;
                float v = facc[rt][ct][q] + b2f(xoldb[off]);
                if (OUTMODE == 0) xbnew[off] = f2b(v);
                else              xnewf[off] = v;
            }
        }
}

extern "C" void kernel_launch(void* const* d_in, const int* in_sizes, int n_in,
                              void* d_out, int out_size, void* d_ws, size_t ws_size,
                              hipStream_t stream) {
    const float* x0   = (const float*)d_in[0];
    const float* Ws_s = (const float*)d_in[1];
    const float* bs_s = (const float*)d_in[2];
    const float* Ws_k = (const float*)d_in[3];
    const float* bs_k = (const float*)d_in[4];
    const int*   src  = (const int*)d_in[5];
    const int*   dst  = src + NE;
    const int*   attr = (const int*)d_in[6];
    float* out = (float*)d_out;

    // workspace carve-up
    ushort* xb0  = (ushort*)d_ws;                        // 12.8 MB each
    ushort* xb1  = xb0 + (size_t)NN * DD;
    ushort* xb2  = xb1 + (size_t)NN * DD;
    ushort* PA   = xb2 + (size_t)NN * DD;                // binned alias pre-G1
    ushort* PB   = PA + (size_t)NN * DD;                 // hist2+off2 alias pre-K1
    ushort* PC   = PB + (size_t)NN * DD;
    ushort* PD   = PC + (size_t)NN * DD;
    ushort* wtb  = PD + (size_t)NN * DD;                 // 9 * 16384 * 2B
    int* ptr    = (int*)(wtb + 9 * 16384);               // 3N+1
    int* part2  = ptr + 3 * NN + 1;                      // 2048
    int* ssrc   = part2 + 2048;                          // NE ints (6 MB)
    uint* binned = (uint*)PA;                            // dead after bucket_finalize
    int* hist2  = (int*)PB;                              // dead after scan
    int* off2   = hist2 + NH2;                           // dead after bucket_finalize

    const int NB2 = (NH2 + 255) / 256;      // 1176

    auto wt = [&](int m) { return wtb + (size_t)m * 16384; };
    auto bk = [&](int t, int k) { return bs_k + ((size_t)t * 3 + k) * DD; };

    // ---------- prologue + binning + CSR (no global atomics) ----------
    prep_all<<<BINB + GCONV + 144, 256, 0, stream>>>(
        dst, attr, hist2, x0, xb0, Ws_s, Ws_k, wtb);
    scan_block<<<NB2, 256, 0, stream>>>(hist2, off2, part2, NH2);
    scan_partials<<<1, 64, 0, stream>>>(part2, NB2);
    scan_add<<<NB2, 256, 0, stream>>>(off2, part2, NH2);
    binB<<<BINB, 256, 0, stream>>>(src, dst, attr, off2, binned);
    bucket_finalize<<<NBUCK, 256, 0, stream>>>(binned, off2, ptr, ssrc);

    // ---------- G1: rel0 @ xb0 ----------
    gather_one<<<GGATH, 256, 0, stream>>>(xb0, 0, ptr, ssrc, PA);

    // ---------- K1: mm0 (xb0,PA -> xb1)  ||  rel1@xb0->PB, rel2@xb0->PC -----
    mm_gather<2, 0, 2><<<GGEMM + 2 * GGATH, 256, 0, stream>>>(
        xb0, PA, nullptr, nullptr,
        wt(0), wt(3), nullptr, nullptr,
        bs_s, bk(0, 0), nullptr, nullptr,
        xb0, nullptr, xb1,
        xb0, 1, PB,
        xb0, 2, PC,
        ptr, ssrc);

    // ---------- G2: rel0 @ xb1 ----------
    gather_one<<<GGATH, 256, 0, stream>>>(xb1, 0, ptr, ssrc, PD);

    // ---------- K2: mm1 (xb1,PD,PB -> xb2)  ||  rel1@xb1->PA ----------
    mm_gather<3, 0, 1><<<GGEMM + GGATH, 256, 0, stream>>>(
        xb1, PD, PB, nullptr,
        wt(1), wt(4), wt(5), nullptr,
        bs_s + DD, bk(1, 0), bk(1, 1), nullptr,
        xb1, nullptr, xb2,
        xb1, 1, PA,
        nullptr, 0, nullptr,
        ptr, ssrc);

    // ---------- G3: rel0 @ xb2 ----------
    gather_one<<<GGATH, 256, 0, stream>>>(xb2, 0, ptr, ssrc, PD);

    // ---------- K3: mm2 (xb2,PD,PA,PC -> out f32) ----------
    mm_gather<4, 1, 0><<<GGEMM, 256, 0, stream>>>(
        xb2, PD, PA, PC,
        wt(2), wt(6), wt(7), wt(8),
        bs_s + 2 * DD, bk(2, 0), bk(2, 1), bk(2, 2),
        xb2, out, nullptr,
        nullptr, 0, nullptr,
        nullptr, 0, nullptr,
        ptr, ssrc);
}

// Round 13
// 262.006 us; speedup vs baseline: 1.1012x; 1.1012x over previous
//
#include <hip/hip_runtime.h>

#define NN 50000
#define NE 1500000
#define DD 128
#define NRANGE ((NN + 255) / 256)      // 196 dst-ranges of 256 nodes
#define NBUCK (3 * NRANGE)             // 588 (rel, range) buckets
#define BINB 512                       // binning blocks (2 per CU)
#define CHUNK ((NE + BINB - 1) / BINB) // 2930 edges per binning block
#define NH2 (NBUCK * BINB)             // 301056 hist2 entries
#define GCONV ((NN * DD / 4 + 255) / 256)  // 6250 to_bf16 blocks

typedef __attribute__((ext_vector_type(8))) short short8;
typedef __attribute__((ext_vector_type(4))) float f32x4;

__device__ __forceinline__ ushort f2b(float x) {
    uint u = __float_as_uint(x);
    u += 0x7FFFu + ((u >> 16) & 1u);
    return (ushort)(u >> 16);
}
__device__ __forceinline__ float b2f(ushort b) {
    return __uint_as_float(((uint)b) << 16);
}

// ---------------- scan helpers ----------------
__global__ __launch_bounds__(256) void scan_block(
    const int* __restrict__ cnt, int* __restrict__ ptr, int* __restrict__ part, int n)
{
    __shared__ int s[256];
    int i = blockIdx.x * 256 + threadIdx.x;
    int v = (i < n) ? cnt[i] : 0;
    s[threadIdx.x] = v;
    __syncthreads();
    #pragma unroll
    for (int off = 1; off < 256; off <<= 1) {
        int t = (threadIdx.x >= off) ? s[threadIdx.x - off] : 0;
        __syncthreads();
        s[threadIdx.x] += t;
        __syncthreads();
    }
    if (i < n) ptr[i] = s[threadIdx.x] - v;
    if (threadIdx.x == 255) part[blockIdx.x] = s[255];
}

__global__ void scan_partials(int* __restrict__ part, int nb)
{
    int lane = threadIdx.x;
    int run = 0;
    for (int base = 0; base < nb; base += 64) {
        int i = base + lane;
        int v = (i < nb) ? part[i] : 0;
        int x = v;
        #pragma unroll
        for (int off = 1; off < 64; off <<= 1) {
            int t = __shfl_up(x, off);
            if (lane >= off) x += t;
        }
        if (i < nb) part[i] = run + x - v;
        run += __shfl(x, 63);
    }
}

// ---------------- fused prologue: histB | to_bf16 | prep_w ----------------
__global__ __launch_bounds__(256) void prep_all(
    const int* __restrict__ dst, const int* __restrict__ attr, int* __restrict__ hist2,
    const float* __restrict__ x, ushort* __restrict__ xb,
    const float* __restrict__ Ws_s, const float* __restrict__ Ws_k, ushort* __restrict__ wt)
{
    __shared__ int lh[NBUCK];
    int b = blockIdx.x, tid = threadIdx.x;
    if (b < BINB) {
        for (int i = tid; i < NBUCK; i += 256) lh[i] = 0;
        __syncthreads();
        int lo = b * CHUNK, hi = lo + CHUNK; if (hi > NE) hi = NE;
        for (int e = lo + tid; e < hi; e += 256)
            atomicAdd(&lh[attr[e] * NRANGE + (dst[e] >> 8)], 1);
        __syncthreads();
        for (int i = tid; i < NBUCK; i += 256) hist2[i * BINB + b] = lh[i];
    } else if (b < BINB + GCONV) {
        int i = (b - BINB) * 256 + tid;
        if (i < NN * DD / 4) {
            float4 v = ((const float4*)x)[i];
            ushort4 o;
            o.x = f2b(v.x); o.y = f2b(v.y); o.z = f2b(v.z); o.w = f2b(v.w);
            ((ushort4*)xb)[i] = o;
        }
    } else {
        int i = (b - BINB - GCONV) * 256 + tid;
        if (i < 9 * 4096) {
            int m = i >> 12;
            int f = (i & 4095) * 4;
            int k = f >> 7, n = f & 127;
            const int tk[6] = {0, 3, 4, 6, 7, 8};
            const float* W = (m < 3) ? (Ws_s + (size_t)m * 16384)
                                     : (Ws_k + (size_t)tk[m - 3] * 16384);
            float4 v = *(const float4*)(W + (size_t)k * DD + n);
            ushort* o = wt + (size_t)m * 16384 + k;
            o[(size_t)(n + 0) * DD] = f2b(v.x);
            o[(size_t)(n + 1) * DD] = f2b(v.y);
            o[(size_t)(n + 2) * DD] = f2b(v.z);
            o[(size_t)(n + 3) * DD] = f2b(v.w);
        }
    }
}

// ---------------- contention-free binning (part2 applied inline) -----------
__global__ __launch_bounds__(256) void binB(
    const int* __restrict__ src, const int* __restrict__ dst, const int* __restrict__ attr,
    const int* __restrict__ off2, const int* __restrict__ part2, uint* __restrict__ binned)
{
    __shared__ int lc[NBUCK];
    int tid = threadIdx.x, blk = blockIdx.x;
    for (int i = tid; i < NBUCK; i += 256) {
        int j = i * BINB + blk;
        lc[i] = off2[j] + part2[j >> 8];
    }
    __syncthreads();
    int lo = blk * CHUNK, hi = lo + CHUNK; if (hi > NE) hi = NE;
    for (int e = lo + tid; e < hi; e += 256) {
        int d = dst[e];
        int b = attr[e] * NRANGE + (d >> 8);
        int pos = atomicAdd(&lc[b], 1);
        binned[pos] = (uint)src[e] | ((uint)(d & 255) << 16);   // src < 2^16
    }
}

// per-bucket: derive per-node CSR ptr (LDS hist+scan) and place edges into ssrc
__global__ __launch_bounds__(256) void bucket_finalize(
    const uint* __restrict__ binned, const int* __restrict__ off2,
    const int* __restrict__ part2, int* __restrict__ ptr, int* __restrict__ ssrc)
{
    __shared__ int lh[256];
    __shared__ int sc[256];
    __shared__ int cur[256];
    int b = blockIdx.x, tid = threadIdx.x;
    int rel = b / NRANGE, r0 = (b % NRANGE) << 8;
    int nloc = NN - r0; if (nloc > 256) nloc = 256;
    int j0 = b * BINB;
    int lo = off2[j0] + part2[j0 >> 8];
    int hi = NE;
    if (b + 1 < NBUCK) {
        int j1 = (b + 1) * BINB;
        hi = off2[j1] + part2[j1 >> 8];
    }
    lh[tid] = 0;
    __syncthreads();
    for (int e = lo + tid; e < hi; e += 256)
        atomicAdd(&lh[(binned[e] >> 16) & 255], 1);
    __syncthreads();
    int v = lh[tid];
    sc[tid] = v;
    __syncthreads();
    #pragma unroll
    for (int off = 1; off < 256; off <<= 1) {
        int t = (tid >= off) ? sc[tid - off] : 0;
        __syncthreads();
        sc[tid] += t;
        __syncthreads();
    }
    int excl = lo + sc[tid] - v;
    if (tid < nloc) ptr[rel * NN + r0 + tid] = excl;
    cur[tid] = excl;
    if (b == NBUCK - 1 && tid == 0) ptr[3 * NN] = NE;
    __syncthreads();
    for (int e = lo + tid; e < hi; e += 256) {
        uint p = binned[e];
        int pos = atomicAdd(&cur[(p >> 16) & 255], 1);
        ssrc[pos] = (int)(p & 0xFFFFu);
    }
}

// ---------------- layer-grouped gather, 2 nodes per wave -------------------
__global__ __launch_bounds__(256) void gather_multi(
    const ushort* __restrict__ h0, const ushort* __restrict__ h1,
    const ushort* __restrict__ h2,
    const int* __restrict__ ptr, const int* __restrict__ ssrc,
    ushort* __restrict__ a0, ushort* __restrict__ a1, ushort* __restrict__ a2)
{
    int rel = blockIdx.y;
    const ushort* h = (rel == 0) ? h0 : ((rel == 1) ? h1 : h2);
    ushort* agg     = (rel == 0) ? a0 : ((rel == 1) ? a1 : a2);

    int tid  = threadIdx.x;
    int half = (tid >> 5) & 1;
    int sub  = tid & 31;
    int n = blockIdx.x * 8 + ((tid >> 6) << 1) + half;
    if (n >= NN) return;
    const int* p = ptr + rel * NN + n;
    int s0 = p[0], s1 = p[1];          // broadcast within half-wave
    float A0 = 0.f, A1 = 0.f, A2 = 0.f, A3 = 0.f;
    int e = s0;
    for (; e + 8 <= s1; e += 8) {
        int idx[8];
        #pragma unroll
        for (int j = 0; j < 8; ++j) idx[j] = ssrc[e + j];
        uint2 v[8];
        #pragma unroll
        for (int j = 0; j < 8; ++j)
            v[j] = ((const uint2*)(h + (size_t)idx[j] * DD))[sub];
        #pragma unroll
        for (int j = 0; j < 8; ++j) {
            A0 += b2f((ushort)(v[j].x & 0xFFFFu)); A1 += b2f((ushort)(v[j].x >> 16));
            A2 += b2f((ushort)(v[j].y & 0xFFFFu)); A3 += b2f((ushort)(v[j].y >> 16));
        }
    }
    if (e + 4 <= s1) {
        int i0 = ssrc[e], i1 = ssrc[e + 1], i2 = ssrc[e + 2], i3 = ssrc[e + 3];
        uint2 v0 = ((const uint2*)(h + (size_t)i0 * DD))[sub];
        uint2 v1 = ((const uint2*)(h + (size_t)i1 * DD))[sub];
        uint2 v2 = ((const uint2*)(h + (size_t)i2 * DD))[sub];
        uint2 v3 = ((const uint2*)(h + (size_t)i3 * DD))[sub];
        A0 += b2f((ushort)(v0.x & 0xFFFFu)); A1 += b2f((ushort)(v0.x >> 16));
        A2 += b2f((ushort)(v0.y & 0xFFFFu)); A3 += b2f((ushort)(v0.y >> 16));
        A0 += b2f((ushort)(v1.x & 0xFFFFu)); A1 += b2f((ushort)(v1.x >> 16));
        A2 += b2f((ushort)(v1.y & 0xFFFFu)); A3 += b2f((ushort)(v1.y >> 16));
        A0 += b2f((ushort)(v2.x & 0xFFFFu)); A1 += b2f((ushort)(v2.x >> 16));
        A2 += b2f((ushort)(v2.y & 0xFFFFu)); A3 += b2f((ushort)(v2.y >> 16));
        A0 += b2f((ushort)(v3.x & 0xFFFFu)); A1 += b2f((ushort)(v3.x >> 16));
        A2 += b2f((ushort)(v3.y & 0xFFFFu)); A3 += b2f((ushort)(v3.y >> 16));
        e += 4;
    }
    for (; e < s1; ++e) {
        int s = ssrc[e];
        uint2 v = ((const uint2*)(h + (size_t)s * DD))[sub];
        A0 += b2f((ushort)(v.x & 0xFFFFu)); A1 += b2f((ushort)(v.x >> 16));
        A2 += b2f((ushort)(v.y & 0xFFFFu)); A3 += b2f((ushort)(v.y >> 16));
    }
    uint2 o;
    o.x = (uint)f2b(A0) | ((uint)f2b(A1) << 16);
    o.y = (uint)f2b(A2) | ((uint)f2b(A3) << 16);
    ((uint2*)(agg + (size_t)n * DD))[sub] = o;
}

// ---------------- fused layer: x_new = x_old + sum_s relu(A_s @ W_s + b_s) ----
// WRITEF=0: write bf16 xbnew only (intermediate layers).
// WRITEF=1: write f32 xnewf only (final layer).
template<int NSRC, int WRITEF>
__global__ __launch_bounds__(256) void layer_mm(
    const ushort* __restrict__ s0, const ushort* __restrict__ s1,
    const ushort* __restrict__ s2, const ushort* __restrict__ s3,
    const ushort* __restrict__ w0, const ushort* __restrict__ w1,
    const ushort* __restrict__ w2, const ushort* __restrict__ w3,
    const float* __restrict__ b0, const float* __restrict__ b1,
    const float* __restrict__ b2, const float* __restrict__ b3,
    const ushort* __restrict__ xoldb, float* __restrict__ xnewf, ushort* __restrict__ xbnew)
{
    __shared__ ushort Atile[64 * 128];   // XOR-swizzled
    const int tid  = threadIdx.x;
    const int wave = tid >> 6, lane = tid & 63;
    const int row0 = blockIdx.x * 64;

    const ushort* srcs[4] = { s0, s1, s2, s3 };
    const ushort* wts[4]  = { w0, w1, w2, w3 };
    const float*  bss[4]  = { b0, b1, b2, b3 };

    float facc[4][2][4];
    #pragma unroll
    for (int rt = 0; rt < 4; ++rt)
        #pragma unroll
        for (int ct = 0; ct < 2; ++ct)
            #pragma unroll
            for (int q = 0; q < 4; ++q) facc[rt][ct][q] = 0.f;

    #pragma unroll
    for (int sidx = 0; sidx < NSRC; ++sidx) {
        const ushort* S = srcs[sidx];
        const ushort* W = wts[sidx];

        __syncthreads();
        for (int i = tid; i < 1024; i += 256) {
            int r = i >> 4, c = i & 15;
            int gr = row0 + r;
            uint4 v = make_uint4(0, 0, 0, 0);
            if (gr < NN) v = ((const uint4*)(S + (size_t)gr * DD))[c];
            int byte = ((r << 8) + (c << 4)) ^ ((r & 7) << 4);
            *((uint4*)((char*)Atile + byte)) = v;
        }
        short8 bfr[2][4];
        #pragma unroll
        for (int ct = 0; ct < 2; ++ct)
            #pragma unroll
            for (int ks = 0; ks < 4; ++ks) {
                int col = (wave << 5) + (ct << 4) + (lane & 15);
                int kb  = (ks << 5) + ((lane >> 4) << 3);
                bfr[ct][ks] = *(const short8*)(W + (size_t)col * DD + kb);
            }
        __syncthreads();

        f32x4 c[4][2];
        #pragma unroll
        for (int rt = 0; rt < 4; ++rt)
            #pragma unroll
            for (int ct = 0; ct < 2; ++ct) c[rt][ct] = (f32x4)(0.f);

        #pragma unroll
        for (int rt = 0; rt < 4; ++rt) {
            int row = (rt << 4) + (lane & 15);
            #pragma unroll
            for (int ks = 0; ks < 4; ++ks) {
                int byte = ((row << 8) + (ks << 6) + ((lane >> 4) << 4)) ^ ((row & 7) << 4);
                short8 a = *((const short8*)((const char*)Atile + byte));
                c[rt][0] = __builtin_amdgcn_mfma_f32_16x16x32_bf16(a, bfr[0][ks], c[rt][0], 0, 0, 0);
                c[rt][1] = __builtin_amdgcn_mfma_f32_16x16x32_bf16(a, bfr[1][ks], c[rt][1], 0, 0, 0);
            }
        }

        const float* B = bss[sidx];
        #pragma unroll
        for (int ct = 0; ct < 2; ++ct) {
            float bb = B[(wave << 5) + (ct << 4) + (lane & 15)];
            #pragma unroll
            for (int rt = 0; rt < 4; ++rt)
                #pragma unroll
                for (int q = 0; q < 4; ++q) {
                    float v = c[rt][ct][q] + bb;
                    facc[rt][ct][q] += v > 0.f ? v : 0.f;
                }
        }
    }

    #pragma unroll
    for (int rt = 0; rt < 4; ++rt)
        #pragma unroll
        for (int q = 0; q < 4; ++q) {
            int row = row0 + (rt << 4) + ((lane >> 4) << 2) + q;
            if (row >= NN) continue;
            #pragma unroll
            for (int ct = 0; ct < 2; ++ct) {
                int col = (wave << 5) + (ct << 4) + (lane & 15);
                size_t off = (size_t)row * DD + col;
                float v = facc[rt][ct][q] + b2f(xoldb[off]);
                if (WRITEF) xnewf[off] = v;
                else        xbnew[off] = f2b(v);
            }
        }
}

extern "C" void kernel_launch(void* const* d_in, const int* in_sizes, int n_in,
                              void* d_out, int out_size, void* d_ws, size_t ws_size,
                              hipStream_t stream) {
    const float* x0   = (const float*)d_in[0];
    const float* Ws_s = (const float*)d_in[1];
    const float* bs_s = (const float*)d_in[2];
    const float* Ws_k = (const float*)d_in[3];
    const float* bs_k = (const float*)d_in[4];
    const int*   src  = (const int*)d_in[5];
    const int*   dst  = src + NE;
    const int*   attr = (const int*)d_in[6];
    float* out = (float*)d_out;

    // workspace carve-up
    ushort* xb0  = (ushort*)d_ws;                        // 12.8 MB each
    ushort* xb1  = xb0 + (size_t)NN * DD;
    ushort* xb2  = xb1 + (size_t)NN * DD;
    ushort* P0   = xb2 + (size_t)NN * DD;                // agg slot (binned alias pre-gather)
    ushort* P1   = P0 + (size_t)NN * DD;                 // agg slot (hist2+off2 alias pre-gather)
    ushort* P2   = P1 + (size_t)NN * DD;                 // agg slot
    ushort* wtb  = P2 + (size_t)NN * DD;                 // 9 * 16384 * 2B
    int* ptr    = (int*)(wtb + 9 * 16384);               // 3N+1
    int* part2  = ptr + 3 * NN + 1;                      // 2048
    int* ssrc   = part2 + 2048;                          // NE ints (6 MB)
    uint* binned = (uint*)P0;                            // NE uints, dead after finalize
    int* hist2  = (int*)P1;                              // NH2 ints, dead after scan
    int* off2   = hist2 + NH2;                           // NH2 ints, dead after finalize

    const int gGemm = (NN + 63) / 64;
    const int gGath = (NN + 7) / 8;
    const int NB2 = (NH2 + 255) / 256;      // 1176

    auto wt = [&](int m) { return wtb + (size_t)m * 16384; };
    auto bk = [&](int t, int k) { return bs_k + ((size_t)t * 3 + k) * DD; };

    // ---------- fused prologue + binning + CSR (no global atomics) ----------
    prep_all<<<BINB + GCONV + 144, 256, 0, stream>>>(
        dst, attr, hist2, x0, xb0, Ws_s, Ws_k, wtb);
    scan_block<<<NB2, 256, 0, stream>>>(hist2, off2, part2, NH2);
    scan_partials<<<1, 64, 0, stream>>>(part2, NB2);
    binB<<<BINB, 256, 0, stream>>>(src, dst, attr, off2, part2, binned);
    bucket_finalize<<<NBUCK, 256, 0, stream>>>(binned, off2, part2, ptr, ssrc);

    // ---------- layer 0 ----------
    gather_multi<<<dim3(gGath, 1), 256, 0, stream>>>(
        xb0, nullptr, nullptr, ptr, ssrc, P0, nullptr, nullptr);
    layer_mm<2, 0><<<gGemm, 256, 0, stream>>>(
        xb0, P0, nullptr, nullptr,
        wt(0), wt(3), nullptr, nullptr,
        bs_s, bk(0, 0), nullptr, nullptr,
        xb0, nullptr, xb1);

    // ---------- layer 1 ----------
    gather_multi<<<dim3(gGath, 2), 256, 0, stream>>>(
        xb1, xb0, nullptr, ptr, ssrc, P0, P1, nullptr);
    layer_mm<3, 0><<<gGemm, 256, 0, stream>>>(
        xb1, P0, P1, nullptr,
        wt(1), wt(4), wt(5), nullptr,
        bs_s + DD, bk(1, 0), bk(1, 1), nullptr,
        xb1, nullptr, xb2);

    // ---------- layer 2 ----------
    gather_multi<<<dim3(gGath, 3), 256, 0, stream>>>(
        xb2, xb1, xb0, ptr, ssrc, P0, P1, P2);
    layer_mm<4, 1><<<gGemm, 256, 0, stream>>>(
        xb2, P0, P1, P2,
        wt(2), wt(6), wt(7), wt(8),
        bs_s + 2 * DD, bk(2, 0), bk(2, 1), bk(2, 2),
        xb2, out, nullptr);
}